// Round 15
// baseline (746.599 us; speedup 1.0000x reference)
//
#include <hip/hip_runtime.h>
#include <cfloat>
#include <stdint.h>

// VQ argmin via exact-split f16 MFMA GEMM — R15: R13 core (best: gemm 135us,
// 72% occupancy) + launch_bounds(256,6) headroom + fused last-arriver reduce.
// cross = z.e as 3-term f16 GEMM: zh*eh + zh*el + zl*eh, e' = e*2^13 (exact pow2),
// dist = fp32(zsq - acc*2^-12) — identical quantization to all passing rounds.
// R14 lesson (2nd confirmation of m141): sched_barrier order-pinning regresses;
// revert to compiler-scheduled K-loop. New: per-mh arrival counter; the 64th
// block of each mh-group reduces its 64 queries in-kernel (threadfence +
// device-scope atomicAdd counter — G16 protocol; 8192 atomics total).
#define KC 8192
#define NQ 8192
#define DD 256
#define NSTAGE 8
#define NT 64              // total k-tiles of 128 codes
#define MT 32              // A prep tiles (256 rows each)

typedef _Float16 f16;
typedef _Float16 half8 __attribute__((ext_vector_type(8)));
typedef float floatx4 __attribute__((ext_vector_type(4)));

// ---- workspace maps ----
#define WS_AH   0
#define WS_AL   4194304
#define WS_BH   8388608
#define WS_BL2  10485760
#define WS_PART2 12582912
#define WS_BL1  12582912
#define WS_PART1 16777216
#define WS_CNT  20971520                    // 128 u32 (fused-reduce mode only)
#define WS_NEED_1PASS 20971520ull           // proven available (R9..R13 ran 1-pass)
#define WS_NEED_FUSED 20972032ull           // +512 B for counters

// ---- device helpers (R4..R13-verified bodies) ----
__device__ __forceinline__ void prep_b_body(const float* __restrict__ cb,
                                            f16* __restrict__ Bh, f16* __restrict__ Bl,
                                            int kofs, int gid) {
    int n = gid & 127;
    int q = (gid >> 7) & 3;
    int s = (gid >> 9) & 7;
    int ntl = gid >> 12;
    int K = kofs + ntl * 128 + n;
    int d0 = s * 32 + q * 8;
    const float4 v0 = *(const float4*)(cb + (size_t)K * DD + d0);
    const float4 v1 = *(const float4*)(cb + (size_t)K * DD + d0 + 4);
    float vv[8] = {v0.x, v0.y, v0.z, v0.w, v1.x, v1.y, v1.z, v1.w};
    half8 eh8, el8;
    #pragma unroll
    for (int j = 0; j < 8; ++j) {
        float e = vv[j] * 8192.0f;               // exact pow2 scale
        f16 h = (f16)e;
        eh8[j] = h;
        el8[j] = (f16)(e - (float)h);
    }
    *(half8*)(Bh + (size_t)gid * 8) = eh8;
    *(half8*)(Bl + (size_t)gid * 8) = el8;
}

__device__ __forceinline__ void prep_a_body(const float* __restrict__ z,
                                            f16* __restrict__ Ah, f16* __restrict__ Al,
                                            int gid) {
    int r = gid & 255;
    int q = (gid >> 8) & 3;
    int s = (gid >> 10) & 7;
    int mt = gid >> 13;
    int Q = mt * 256 + r;
    int b = Q >> 10, t = Q & 1023;
    const float* zp = z + (size_t)b * (DD * 1024) + t;
    int d0 = s * 32 + q * 8;
    half8 zh8, zl8;
    #pragma unroll
    for (int j = 0; j < 8; ++j) {
        float v = zp[(size_t)(d0 + j) * 1024];   // lane varies t -> coalesced
        f16 h = (f16)v;
        zh8[j] = h;
        zl8[j] = (f16)(v - (float)h);            // exact fp32 residual
    }
    *(half8*)(Ah + (size_t)gid * 8) = zh8;
    *(half8*)(Al + (size_t)gid * 8) = zl8;
}

__device__ __forceinline__ void zsq_body(const float* __restrict__ z,
                                         float* __restrict__ zsq, int q) {
    int b = q >> 10, t = q & 1023;
    const float* p = z + (size_t)b * (DD * 1024) + t;
    float s0 = 0.f, s1 = 0.f;
    #pragma unroll 8
    for (int d = 0; d < 128; ++d) { float v = p[(size_t)d * 1024]; s0 = fmaf(v, v, s0); }
    #pragma unroll 8
    for (int d = 128; d < 256; ++d) { float v = p[(size_t)d * 1024]; s1 = fmaf(v, v, s1); }
    zsq[q] = s0 + s1;    // identical chain to R1..R13 passers
}

// ---- fused prep: blocks [0,1024) B | [1024,2048) A | [2048,2080) zsq (+cnt zero) ----
__global__ void vq_prep_all(const float* __restrict__ z, const float* __restrict__ cb,
                            f16* __restrict__ Ah, f16* __restrict__ Al,
                            f16* __restrict__ Bh, f16* __restrict__ Bl,
                            float* __restrict__ zsq, unsigned int* __restrict__ cnt) {
    int bid = blockIdx.x;
    int tid = threadIdx.x;
    if (bid < 1024) {
        prep_b_body(cb, Bh, Bl, 0, bid * 256 + tid);
    } else if (bid < 2048) {
        prep_a_body(z, Ah, Al, (bid - 1024) * 256 + tid);
    } else {
        zsq_body(z, zsq, (bid - 2048) * 256 + tid);
        if (cnt && bid == 2048 && tid < 128) cnt[tid] = 0u;   // arrival counters
    }
}

// standalone preps for the 2-pass fallback
__global__ void vq_prep_a(const float* __restrict__ z,
                          f16* __restrict__ Ah, f16* __restrict__ Al) {
    prep_a_body(z, Ah, Al, blockIdx.x * 256 + threadIdx.x);
}
__global__ void vq_prep_b(const float* __restrict__ cb,
                          f16* __restrict__ Bh, f16* __restrict__ Bl, int kofs) {
    prep_b_body(cb, Bh, Bl, kofs, blockIdx.x * 256 + threadIdx.x);
}
__global__ void vq_zsq(const float* __restrict__ z, float* __restrict__ zsq) {
    zsq_body(z, zsq, blockIdx.x * 256 + threadIdx.x);
}

// ---- main GEMM: R13 body (64x128 block, 4 waves of 64x32, term-major MFMA),
//      launch_bounds(256,6), optional fused last-arriver reduce tail ----
__global__ __launch_bounds__(256, 6)
void vq_gemm11(const f16* __restrict__ Ah, const f16* __restrict__ Al,
               const f16* __restrict__ Bh, const f16* __restrict__ Bl,
               const float* __restrict__ zsq, unsigned long long* __restrict__ part_p,
               int kofs, unsigned int* __restrict__ cnt, int* __restrict__ out) {
    // Swizzle (R13-verified): per XCD, 8-ntl B chunks x 16 mh A-strips.
    const int flat = blockIdx.x;
    const int xcd = flat & 7;
    const int idx = flat >> 3;
    const int mh  = xcd * 16 + ((idx >> 3) & 15);   // 0..127, 64-row strip
    const int ntl = (idx >> 7) * 8 + (idx & 7);     // 0..63 / 0..31
    const int tid = threadIdx.x;
    const int lane = tid & 63;
    const int wn = tid >> 6;                        // 4 waves: 32-col strips
    const int quad = lane >> 4;
    const int l16 = lane & 15;

    __shared__ unsigned long long kbuf[256];        // [4][64] merge buffer
    __shared__ int is_last;

    floatx4 acc[4][2];
    #pragma unroll
    for (int i = 0; i < 4; ++i) {
        acc[i][0] = (floatx4)0.f;
        acc[i][1] = (floatx4)0.f;
    }

    const int mt = mh >> 2;
    const size_t arbase = (size_t)((mh & 3) * 64 + l16) * 8;
    const f16* Apb = Ah + ((size_t)(mt * 8) * 4 + quad) * 2048 + arbase;
    const f16* Alb = Al + ((size_t)(mt * 8) * 4 + quad) * 2048 + arbase;
    const f16* Bpb = Bh + ((size_t)(ntl * 8) * 4 + quad) * 1024 + (size_t)(wn * 32 + l16) * 8;
    const f16* Blb = Bl + ((size_t)(ntl * 8) * 4 + quad) * 1024 + (size_t)(wn * 32 + l16) * 8;

    #pragma unroll
    for (int s = 0; s < NSTAGE; ++s) {
        const f16* As  = Apb + (size_t)s * 8192;
        const f16* Als = Alb + (size_t)s * 8192;
        const f16* Bs  = Bpb + (size_t)s * 4096;
        const f16* Bls = Blb + (size_t)s * 4096;
        half8 av[4], aw[4], bhf[2], blf[2];
        #pragma unroll
        for (int nj = 0; nj < 2; ++nj) {
            bhf[nj] = *(const half8*)(Bs + nj * 128);
            blf[nj] = *(const half8*)(Bls + nj * 128);
        }
        #pragma unroll
        for (int mi = 0; mi < 4; ++mi) {
            av[mi] = *(const half8*)(As + mi * 128);
            aw[mi] = *(const half8*)(Als + mi * 128);
        }
        // term-major: 8 independent MFMAs between any dependent pair
        #pragma unroll
        for (int mi = 0; mi < 4; ++mi)
            #pragma unroll
            for (int nj = 0; nj < 2; ++nj)
                acc[mi][nj] = __builtin_amdgcn_mfma_f32_16x16x32_f16(av[mi], bhf[nj], acc[mi][nj], 0, 0, 0);
        #pragma unroll
        for (int mi = 0; mi < 4; ++mi)
            #pragma unroll
            for (int nj = 0; nj < 2; ++nj)
                acc[mi][nj] = __builtin_amdgcn_mfma_f32_16x16x32_f16(av[mi], blf[nj], acc[mi][nj], 0, 0, 0);
        #pragma unroll
        for (int mi = 0; mi < 4; ++mi)
            #pragma unroll
            for (int nj = 0; nj < 2; ++nj)
                acc[mi][nj] = __builtin_amdgcn_mfma_f32_16x16x32_f16(aw[mi], bhf[nj], acc[mi][nj], 0, 0, 0);
    }

    // ---- epilogue (verified maps): dist quantization + 4-way LDS merge ----
    const int kb = kofs + ntl * 128 + wn * 32;
    #pragma unroll
    for (int mi = 0; mi < 4; ++mi) {
        #pragma unroll
        for (int reg = 0; reg < 4; ++reg) {
            int qlocal = mi * 16 + quad * 4 + reg;   // verified C/D map
            float zq = zsq[mh * 64 + qlocal];
            float bd = FLT_MAX; int bk = 0;
            #pragma unroll
            for (int nj = 0; nj < 2; ++nj) {         // ascending k: '<' keeps lowest
                float dd = zq - acc[mi][nj][reg] * 0x1p-12f;  // single fp32 rounding
                int kk = kb + nj * 16 + l16;
                if (dd < bd || (dd == bd && kk < bk)) { bd = dd; bk = kk; }
            }
            #pragma unroll
            for (int mm = 1; mm <= 8; mm <<= 1) {    // 16-lane butterfly, same q
                float od = __shfl_xor(bd, mm, 64);
                int ok = __shfl_xor(bk, mm, 64);
                if (od < bd || (od == bd && ok < bk)) { bd = od; bk = ok; }
            }
            if (l16 == 0)
                kbuf[wn * 64 + qlocal] =
                    ((unsigned long long)__float_as_uint(bd) << 32) | (unsigned int)bk;
        }
    }
    __syncthreads();
    if (tid < 64) {
        unsigned long long k0 = kbuf[tid];
        unsigned long long k1 = kbuf[64 + tid];
        unsigned long long k2 = kbuf[128 + tid];
        unsigned long long k3 = kbuf[192 + tid];
        unsigned long long key = (k1 < k0) ? k1 : k0;
        if (k2 < key) key = k2;
        if (k3 < key) key = k3;
        part_p[(size_t)ntl * NQ + mh * 64 + tid] = key;   // coalesced 512B store
    }

    // ---- fused last-arriver reduce (1-pass+cnt mode only; G16 fence protocol) ----
    if (cnt) {
        __threadfence();                              // publish part stores
        if (tid == 0)
            is_last = (atomicAdd(&cnt[mh], 1u) == 63u);  // device-scope
        __syncthreads();
        if (is_last) {
            __threadfence();                          // acquire all 64 rows
            if (tid < 64) {
                int q = mh * 64 + tid;
                unsigned long long best = part_p[q];
                #pragma unroll 8
                for (int s = 1; s < NT; ++s) {        // coalesced 512B per row
                    unsigned long long k2 = part_p[(size_t)s * NQ + q];
                    if (k2 < best) best = k2;
                }
                out[q] = (int)(best & 0xFFFFFFFFull); // overwrites zsq[q]: all
            }                                         // readers of q finished
        }
    }
}

__global__ void vq_reduce64(const unsigned long long* __restrict__ part,
                            int* __restrict__ out) {
    int q = blockIdx.x * 256 + threadIdx.x;
    unsigned long long best = part[q];
    #pragma unroll 8
    for (int s = 1; s < NT; ++s) {
        unsigned long long k2 = part[(size_t)s * NQ + q];
        if (k2 < best) best = k2;
    }
    out[q] = (int)(best & 0xFFFFFFFFull);
}

extern "C" void kernel_launch(void* const* d_in, const int* in_sizes, int n_in,
                              void* d_out, int out_size, void* d_ws, size_t ws_size,
                              hipStream_t stream) {
    const float* z  = (const float*)d_in[0];   // (8, 256, 1024) fp32
    const float* cb = (const float*)d_in[1];   // (8192, 256) fp32
    char* ws = (char*)d_ws;
    f16* Ah = (f16*)(ws + WS_AH);
    f16* Al = (f16*)(ws + WS_AL);
    // zsq parked in d_out (32 KB): read by gemm, overwritten by fused reduce.
    float* zsq = (float*)d_out;
    int* out = (int*)d_out;

    if (ws_size >= WS_NEED_1PASS) {
        f16* Bh = (f16*)(ws + WS_BH);
        f16* Bl = (f16*)(ws + WS_BL1);
        unsigned long long* part = (unsigned long long*)(ws + WS_PART1);
        unsigned int* cnt = (ws_size >= WS_NEED_FUSED)
                          ? (unsigned int*)(ws + WS_CNT) : nullptr;
        vq_prep_all<<<2080, 256, 0, stream>>>(z, cb, Ah, Al, Bh, Bl, zsq, cnt);
        vq_gemm11<<<8192, 256, 0, stream>>>(Ah, Al, Bh, Bl, zsq, part, 0, cnt, out);
        if (!cnt)
            vq_reduce64<<<NQ / 256, 256, 0, stream>>>(part, out);
    } else {
        // 2-pass fallback under the proven 16.875 MB floor (B buffer reused)
        f16* Bh = (f16*)(ws + WS_BH);
        f16* Bl = (f16*)(ws + WS_BL2);
        unsigned long long* part = (unsigned long long*)(ws + WS_PART2);
        vq_zsq<<<NQ / 256, 256, 0, stream>>>(z, zsq);
        vq_prep_a<<<1024, 256, 0, stream>>>(z, Ah, Al);
        for (int p = 0; p < 2; ++p) {
            int kofs = p * 4096;
            vq_prep_b<<<512, 256, 0, stream>>>(cb, Bh, Bl, kofs);
            vq_gemm11<<<4096, 256, 0, stream>>>(Ah, Al, Bh, Bl, zsq,
                                                part + (size_t)p * 32 * NQ, kofs,
                                                nullptr, out);
        }
        vq_reduce64<<<NQ / 256, 256, 0, stream>>>(part, out);
    }
}

// Round 16
// 219.321 us; speedup vs baseline: 3.4041x; 3.4041x over previous
//
#include <hip/hip_runtime.h>
#include <cfloat>
#include <stdint.h>

// VQ argmin via exact-split f16 MFMA GEMM — R16: R13 core (best verified:
// 212.6us total, gemm 135us @ 72% occupancy) + sched_group_barrier clustering
// (12 VMEM reads then 24 MFMAs per K-stage) to force batched loads.
// cross = z.e as 3-term f16 GEMM: zh*eh + zh*el + zl*eh, e' = e*2^13 (exact pow2),
// dist = fp32(zsq - acc*2^-12) — identical quantization to all passing rounds.
// R15 lesson: __threadfence() (device-scope) = L2 writeback/invalidate storm on
// multi-XCD — never inside a hot kernel. R14 lesson: sched_barrier(0) order-pinning
// regresses. sched_group_barrier is the soft variant (m137: neutral, not harmful).
#define KC 8192
#define NQ 8192
#define DD 256
#define NSTAGE 8
#define NT 64              // total k-tiles of 128 codes
#define MT 32              // A prep tiles (256 rows each)

typedef _Float16 f16;
typedef _Float16 half8 __attribute__((ext_vector_type(8)));
typedef float floatx4 __attribute__((ext_vector_type(4)));

// ---- workspace maps ----
#define WS_AH   0
#define WS_AL   4194304
#define WS_BH   8388608
#define WS_BL2  10485760
#define WS_PART2 12582912
#define WS_BL1  12582912
#define WS_PART1 16777216
#define WS_NEED_1PASS 20971520ull

// ---- device helpers (R4..R13-verified bodies) ----
__device__ __forceinline__ void prep_b_body(const float* __restrict__ cb,
                                            f16* __restrict__ Bh, f16* __restrict__ Bl,
                                            int kofs, int gid) {
    int n = gid & 127;
    int q = (gid >> 7) & 3;
    int s = (gid >> 9) & 7;
    int ntl = gid >> 12;
    int K = kofs + ntl * 128 + n;
    int d0 = s * 32 + q * 8;
    const float4 v0 = *(const float4*)(cb + (size_t)K * DD + d0);
    const float4 v1 = *(const float4*)(cb + (size_t)K * DD + d0 + 4);
    float vv[8] = {v0.x, v0.y, v0.z, v0.w, v1.x, v1.y, v1.z, v1.w};
    half8 eh8, el8;
    #pragma unroll
    for (int j = 0; j < 8; ++j) {
        float e = vv[j] * 8192.0f;               // exact pow2 scale
        f16 h = (f16)e;
        eh8[j] = h;
        el8[j] = (f16)(e - (float)h);
    }
    *(half8*)(Bh + (size_t)gid * 8) = eh8;
    *(half8*)(Bl + (size_t)gid * 8) = el8;
}

__device__ __forceinline__ void prep_a_body(const float* __restrict__ z,
                                            f16* __restrict__ Ah, f16* __restrict__ Al,
                                            int gid) {
    int r = gid & 255;
    int q = (gid >> 8) & 3;
    int s = (gid >> 10) & 7;
    int mt = gid >> 13;
    int Q = mt * 256 + r;
    int b = Q >> 10, t = Q & 1023;
    const float* zp = z + (size_t)b * (DD * 1024) + t;
    int d0 = s * 32 + q * 8;
    half8 zh8, zl8;
    #pragma unroll
    for (int j = 0; j < 8; ++j) {
        float v = zp[(size_t)(d0 + j) * 1024];   // lane varies t -> coalesced
        f16 h = (f16)v;
        zh8[j] = h;
        zl8[j] = (f16)(v - (float)h);            // exact fp32 residual
    }
    *(half8*)(Ah + (size_t)gid * 8) = zh8;
    *(half8*)(Al + (size_t)gid * 8) = zl8;
}

__device__ __forceinline__ void zsq_body(const float* __restrict__ z,
                                         float* __restrict__ zsq, int q) {
    int b = q >> 10, t = q & 1023;
    const float* p = z + (size_t)b * (DD * 1024) + t;
    float s0 = 0.f, s1 = 0.f;
    #pragma unroll 8
    for (int d = 0; d < 128; ++d) { float v = p[(size_t)d * 1024]; s0 = fmaf(v, v, s0); }
    #pragma unroll 8
    for (int d = 128; d < 256; ++d) { float v = p[(size_t)d * 1024]; s1 = fmaf(v, v, s1); }
    zsq[q] = s0 + s1;    // identical chain to R1..R13 passers
}

// ---- fused prep: blocks [0,1024) B | [1024,2048) A | [2048,2080) zsq ----
__global__ void vq_prep_all(const float* __restrict__ z, const float* __restrict__ cb,
                            f16* __restrict__ Ah, f16* __restrict__ Al,
                            f16* __restrict__ Bh, f16* __restrict__ Bl,
                            float* __restrict__ zsq) {
    int bid = blockIdx.x;
    int tid = threadIdx.x;
    if (bid < 1024) {
        prep_b_body(cb, Bh, Bl, 0, bid * 256 + tid);
    } else if (bid < 2048) {
        prep_a_body(z, Ah, Al, (bid - 1024) * 256 + tid);
    } else {
        zsq_body(z, zsq, (bid - 2048) * 256 + tid);
    }
}

// standalone preps for the 2-pass fallback
__global__ void vq_prep_a(const float* __restrict__ z,
                          f16* __restrict__ Ah, f16* __restrict__ Al) {
    prep_a_body(z, Ah, Al, blockIdx.x * 256 + threadIdx.x);
}
__global__ void vq_prep_b(const float* __restrict__ cb,
                          f16* __restrict__ Bh, f16* __restrict__ Bl, int kofs) {
    prep_b_body(cb, Bh, Bl, kofs, blockIdx.x * 256 + threadIdx.x);
}
__global__ void vq_zsq(const float* __restrict__ z, float* __restrict__ zsq) {
    zsq_body(z, zsq, blockIdx.x * 256 + threadIdx.x);
}

// ---- main GEMM: 64x128 block, 4 waves of 64x32, term-major MFMA,
//      sched_group_barrier-clustered stages ----
__global__ __launch_bounds__(256, 4)
void vq_gemm12(const f16* __restrict__ Ah, const f16* __restrict__ Al,
               const f16* __restrict__ Bh, const f16* __restrict__ Bl,
               const float* __restrict__ zsq, unsigned long long* __restrict__ part_p,
               int kofs) {
    // Swizzle (R13-verified): per XCD, 8-ntl B chunks x 16 mh A-strips.
    const int flat = blockIdx.x;
    const int xcd = flat & 7;
    const int idx = flat >> 3;
    const int mh  = xcd * 16 + ((idx >> 3) & 15);   // 0..127, 64-row strip
    const int ntl = (idx >> 7) * 8 + (idx & 7);     // 0..63 / 0..31
    const int tid = threadIdx.x;
    const int lane = tid & 63;
    const int wn = tid >> 6;                        // 4 waves: 32-col strips
    const int quad = lane >> 4;
    const int l16 = lane & 15;

    __shared__ unsigned long long kbuf[256];        // [4][64] merge buffer

    floatx4 acc[4][2];
    #pragma unroll
    for (int i = 0; i < 4; ++i) {
        acc[i][0] = (floatx4)0.f;
        acc[i][1] = (floatx4)0.f;
    }

    const int mt = mh >> 2;
    const size_t arbase = (size_t)((mh & 3) * 64 + l16) * 8;
    const f16* Apb = Ah + ((size_t)(mt * 8) * 4 + quad) * 2048 + arbase;
    const f16* Alb = Al + ((size_t)(mt * 8) * 4 + quad) * 2048 + arbase;
    const f16* Bpb = Bh + ((size_t)(ntl * 8) * 4 + quad) * 1024 + (size_t)(wn * 32 + l16) * 8;
    const f16* Blb = Bl + ((size_t)(ntl * 8) * 4 + quad) * 1024 + (size_t)(wn * 32 + l16) * 8;

    #pragma unroll
    for (int s = 0; s < NSTAGE; ++s) {
        const f16* As  = Apb + (size_t)s * 8192;
        const f16* Als = Alb + (size_t)s * 8192;
        const f16* Bs  = Bpb + (size_t)s * 4096;
        const f16* Bls = Blb + (size_t)s * 4096;
        half8 av[4], aw[4], bhf[2], blf[2];          // 48 operand VGPRs
        #pragma unroll
        for (int nj = 0; nj < 2; ++nj) {
            bhf[nj] = *(const half8*)(Bs + nj * 128);
            blf[nj] = *(const half8*)(Bls + nj * 128);
        }
        #pragma unroll
        for (int mi = 0; mi < 4; ++mi) {
            av[mi] = *(const half8*)(As + mi * 128);
            aw[mi] = *(const half8*)(Als + mi * 128);
        }
        // term-major: 8 independent MFMAs between any dependent pair
        #pragma unroll
        for (int mi = 0; mi < 4; ++mi)
            #pragma unroll
            for (int nj = 0; nj < 2; ++nj)
                acc[mi][nj] = __builtin_amdgcn_mfma_f32_16x16x32_f16(av[mi], bhf[nj], acc[mi][nj], 0, 0, 0);
        #pragma unroll
        for (int mi = 0; mi < 4; ++mi)
            #pragma unroll
            for (int nj = 0; nj < 2; ++nj)
                acc[mi][nj] = __builtin_amdgcn_mfma_f32_16x16x32_f16(av[mi], blf[nj], acc[mi][nj], 0, 0, 0);
        #pragma unroll
        for (int mi = 0; mi < 4; ++mi)
            #pragma unroll
            for (int nj = 0; nj < 2; ++nj)
                acc[mi][nj] = __builtin_amdgcn_mfma_f32_16x16x32_f16(aw[mi], bhf[nj], acc[mi][nj], 0, 0, 0);
        // Soft scheduling hint (m137-proven safe): cluster this stage as
        // 12 VMEM reads followed by 24 MFMAs -> all 12 loads in flight at once,
        // one latency exposure per 466-cyc MFMA block instead of twelve.
        __builtin_amdgcn_sched_group_barrier(0x020, 12, 0);  // VMEM read x12
        __builtin_amdgcn_sched_group_barrier(0x008, 24, 0);  // MFMA x24
    }

    // ---- epilogue (verified maps): dist quantization + 4-way LDS merge ----
    const int kb = kofs + ntl * 128 + wn * 32;
    #pragma unroll
    for (int mi = 0; mi < 4; ++mi) {
        #pragma unroll
        for (int reg = 0; reg < 4; ++reg) {
            int qlocal = mi * 16 + quad * 4 + reg;   // verified C/D map
            float zq = zsq[mh * 64 + qlocal];
            float bd = FLT_MAX; int bk = 0;
            #pragma unroll
            for (int nj = 0; nj < 2; ++nj) {         // ascending k: '<' keeps lowest
                float dd = zq - acc[mi][nj][reg] * 0x1p-12f;  // single fp32 rounding
                int kk = kb + nj * 16 + l16;
                if (dd < bd || (dd == bd && kk < bk)) { bd = dd; bk = kk; }
            }
            #pragma unroll
            for (int mm = 1; mm <= 8; mm <<= 1) {    // 16-lane butterfly, same q
                float od = __shfl_xor(bd, mm, 64);
                int ok = __shfl_xor(bk, mm, 64);
                if (od < bd || (od == bd && ok < bk)) { bd = od; bk = ok; }
            }
            if (l16 == 0)
                kbuf[wn * 64 + qlocal] =
                    ((unsigned long long)__float_as_uint(bd) << 32) | (unsigned int)bk;
        }
    }
    __syncthreads();
    if (tid < 64) {
        unsigned long long k0 = kbuf[tid];
        unsigned long long k1 = kbuf[64 + tid];
        unsigned long long k2 = kbuf[128 + tid];
        unsigned long long k3 = kbuf[192 + tid];
        unsigned long long key = (k1 < k0) ? k1 : k0;
        if (k2 < key) key = k2;
        if (k3 < key) key = k3;
        part_p[(size_t)ntl * NQ + mh * 64 + tid] = key;   // coalesced 512B store
    }
}

__global__ void vq_reduce64(const unsigned long long* __restrict__ part,
                            int* __restrict__ out) {
    int q = blockIdx.x * 256 + threadIdx.x;
    unsigned long long best = part[q];
    #pragma unroll 8
    for (int s = 1; s < NT; ++s) {                  // coalesced per-row reads
        unsigned long long k2 = part[(size_t)s * NQ + q];
        if (k2 < best) best = k2;
    }
    out[q] = (int)(best & 0xFFFFFFFFull);
}

extern "C" void kernel_launch(void* const* d_in, const int* in_sizes, int n_in,
                              void* d_out, int out_size, void* d_ws, size_t ws_size,
                              hipStream_t stream) {
    const float* z  = (const float*)d_in[0];   // (8, 256, 1024) fp32
    const float* cb = (const float*)d_in[1];   // (8192, 256) fp32
    char* ws = (char*)d_ws;
    f16* Ah = (f16*)(ws + WS_AH);
    f16* Al = (f16*)(ws + WS_AL);
    // zsq parked in d_out (32 KB): read by gemm, overwritten by reduce.
    float* zsq = (float*)d_out;
    int* out = (int*)d_out;

    if (ws_size >= WS_NEED_1PASS) {
        f16* Bh = (f16*)(ws + WS_BH);
        f16* Bl = (f16*)(ws + WS_BL1);
        unsigned long long* part = (unsigned long long*)(ws + WS_PART1);
        vq_prep_all<<<2080, 256, 0, stream>>>(z, cb, Ah, Al, Bh, Bl, zsq);
        vq_gemm12<<<8192, 256, 0, stream>>>(Ah, Al, Bh, Bl, zsq, part, 0);
        vq_reduce64<<<NQ / 256, 256, 0, stream>>>(part, out);
    } else {
        // 2-pass fallback under the proven 16.875 MB floor (B buffer reused)
        f16* Bh = (f16*)(ws + WS_BH);
        f16* Bl = (f16*)(ws + WS_BL2);
        unsigned long long* part = (unsigned long long*)(ws + WS_PART2);
        vq_zsq<<<NQ / 256, 256, 0, stream>>>(z, zsq);
        vq_prep_a<<<1024, 256, 0, stream>>>(z, Ah, Al);
        for (int p = 0; p < 2; ++p) {
            int kofs = p * 4096;
            vq_prep_b<<<512, 256, 0, stream>>>(cb, Bh, Bl, kofs);
            vq_gemm12<<<4096, 256, 0, stream>>>(Ah, Al, Bh, Bl, zsq,
                                                part + (size_t)p * 32 * NQ, kofs);
        }
        vq_reduce64<<<NQ / 256, 256, 0, stream>>>(part, out);
    }
}